// Round 7
// baseline (402.354 us; speedup 1.0000x reference)
//
#include <hip/hip_runtime.h>
#include <math.h>

// Problem geometry (fixed by reference)
#define N_ROWS 32768          // 32 * 32 * 32 (B*H*W)
#define K_CODES 1024
#define C_DIM 256
#define HW 1024               // H*W = 32*32

// d_out layout (float elements), tuple concatenated flat in return order:
// distances [N,K] | indices [N] (as float) | encodings [N,K] | perplexity [1]
#define OFF_DIST 0
#define OFF_IDX  (N_ROWS * K_CODES)
#define OFF_ENC  (OFF_IDX + N_ROWS)
#define OFF_PERP (OFF_ENC + N_ROWS * K_CODES)

typedef __attribute__((ext_vector_type(8))) short short8;   // 8 bf16 (4 VGPR)
typedef __attribute__((ext_vector_type(4))) float f32x4;    // MFMA acc

// ---- bf16 split helpers (bit-level, round-to-nearest-even) ------------------
__device__ inline unsigned short bf16_rn(float x) {
    unsigned int u = __float_as_uint(x);
    unsigned int r = u + 0x7FFFu + ((u >> 16) & 1u);
    return (unsigned short)(r >> 16);
}
__device__ inline float bf16_to_f(unsigned short h) {
    return __uint_as_float(((unsigned int)h) << 16);
}

// ---- async global->LDS, 16B per lane (dest = wave-uniform base + lane*16) ---
__device__ __forceinline__ void gl2lds16(const unsigned short* g, char* l) {
    __builtin_amdgcn_global_load_lds(
        (const __attribute__((address_space(1))) unsigned int*)g,
        (__attribute__((address_space(3))) unsigned int*)l, 16, 0, 0);
}

// ------- fused prep: z NCHW->NHWC hi/lo + zsq  |  codebook hi/lo + esq -------
// blocks 0..255: z role (b = bid>>3, hw-tile = bid&7). blocks 256..511: cb.
__global__ __launch_bounds__(256) void prep_kernel(
        const float* __restrict__ z, const float* __restrict__ cb,
        unsigned short* __restrict__ z_hi, unsigned short* __restrict__ z_lo,
        unsigned short* __restrict__ cb_hi, unsigned short* __restrict__ cb_lo,
        float* __restrict__ zsq, float* __restrict__ esq) {
    const int bid = blockIdx.x;
    const int t = threadIdx.x;

    if (bid >= 256) {          // ---- codebook role: wave per row ----
        const int lane = t & 63;
        const int k = (bid - 256) * 4 + (t >> 6);
        float4 v = *reinterpret_cast<const float4*>(cb + (size_t)k * C_DIM + lane * 4);
        float s = v.x * v.x + v.y * v.y + v.z * v.z + v.w * v.w;
        ushort4 h, l;
        h.x = bf16_rn(v.x); l.x = bf16_rn(v.x - bf16_to_f(h.x));
        h.y = bf16_rn(v.y); l.y = bf16_rn(v.y - bf16_to_f(h.y));
        h.z = bf16_rn(v.z); l.z = bf16_rn(v.z - bf16_to_f(h.z));
        h.w = bf16_rn(v.w); l.w = bf16_rn(v.w - bf16_to_f(h.w));
        *reinterpret_cast<ushort4*>(cb_hi + (size_t)k * C_DIM + lane * 4) = h;
        *reinterpret_cast<ushort4*>(cb_lo + (size_t)k * C_DIM + lane * 4) = l;
#pragma unroll
        for (int m = 1; m < 64; m <<= 1) s += __shfl_xor(s, m);
        if (lane == 0) esq[k] = s;
        return;
    }

    // ---- z role: LDS-tiled NCHW -> NHWC transpose + hi/lo split + zsq ----
    __shared__ float st[64][132];          // [c][hw]
    const int b = bid >> 3;
    const int hw0 = (bid & 7) * 128;

    const int c_r  = t >> 5;               // 0..7  (read role)
    const int hw_r = (t & 31) * 4;
    const int hw_w = t >> 1;               // 0..127 (write role)
    const int ch   = (t & 1) * 32;
    const int n    = b * HW + hw0 + hw_w;

    float zacc = 0.f;

    for (int c0 = 0; c0 < C_DIM; c0 += 64) {
#pragma unroll
        for (int it = 0; it < 8; ++it) {
            int c_l = it * 8 + c_r;
            float4 v = *reinterpret_cast<const float4*>(
                z + (size_t)b * (C_DIM * HW) + (size_t)(c0 + c_l) * HW + hw0 + hw_r);
            *reinterpret_cast<float4*>(&st[c_l][hw_r]) = v;
        }
        __syncthreads();

        short8 hv[4], lv[4];
#pragma unroll
        for (int j = 0; j < 32; ++j) {
            float x = st[ch + j][hw_w];
            unsigned short h = bf16_rn(x);
            unsigned short lo = bf16_rn(x - bf16_to_f(h));
            hv[j >> 3][j & 7] = (short)h;
            lv[j >> 3][j & 7] = (short)lo;
            zacc = fmaf(x, x, zacc);
        }
        unsigned short* hp = z_hi + (size_t)n * C_DIM + c0 + ch;
        unsigned short* lp = z_lo + (size_t)n * C_DIM + c0 + ch;
#pragma unroll
        for (int q = 0; q < 4; ++q) {
            *reinterpret_cast<short8*>(hp + q * 8) = hv[q];
            *reinterpret_cast<short8*>(lp + q * 8) = lv[q];
        }
        __syncthreads();
    }
    float o = __shfl_xor(zacc, 1);
    if ((t & 1) == 0) zsq[n] = zacc + o;
}

// -------- distances: bf16 GEMM over virtual K=768, counted-vmcnt ring --------
// 128x256 tile, BK=32, 8 waves (2x4, 64x64 each). 3-buffer LDS ring fed by
// global_load_lds(16B); raw s_barrier + s_waitcnt vmcnt(3) (never 0 in loop).
// LDS involution swizzle: oct' = oct ^ ((row>>1)&3)  (byte bits 4-5 ^= row
// bits 1-2) applied on the pre-swizzled global SOURCE and on ds_read addrs
// (rule #21: linear gl2lds dest). Quarter-wave reads spread over all 8
// 16B-slots -> 2-way (free) instead of 8-way (2.94x).
// Virtual K: steps 0-7 = Ah*Bh, 8-15 = Ah*Bl, 16-23 = Al*Bh (c0 = (s&7)*32).
// Grid 1024 = 256 row-tiles x 4 col-tiles, XCD-swizzled (col-tile fastest).
#define KSTEPS 24

__global__ __launch_bounds__(512, 4) void dist_mfma_kernel(
        const unsigned short* __restrict__ z_hi,
        const unsigned short* __restrict__ z_lo,
        const unsigned short* __restrict__ cb_hi,
        const unsigned short* __restrict__ cb_lo,
        const float* __restrict__ zsq, const float* __restrict__ esq,
        float* __restrict__ dist, float2* __restrict__ partial) {
    __shared__ __align__(16) unsigned short As[3][128 * 32];   // 24 KB
    __shared__ __align__(16) unsigned short Bs[3][256 * 32];   // 48 KB
    __shared__ float2 pb[128][4];                              //  4 KB

    const int t = threadIdx.x;
    const int lane = t & 63, wid = t >> 6;
    const int wy = wid >> 2, wx = wid & 3;      // 2 x 4 wave grid
    const int l15 = lane & 15, l4 = lane >> 4;

    // XCD-aware swizzle: 1024 blocks, 8 XCDs, 128 contiguous per XCD.
    const int swz = (blockIdx.x & 7) * 128 + (blockIdx.x >> 3);
    const int kbi = swz & 3;                    // col tile fastest -> shares A
    const int kb = kbi * 256;
    const int nb = (swz >> 2) * 128;

    // staging roles (thread-constant)
    const int srow = t >> 2;                               // 0..127
    const int soct = ((t & 3) ^ ((t >> 3) & 3)) * 8;       // swizzled source oct
    const int wb   = (t & ~63) * 16;                       // wave LDS base

    // ds_read swizzle offset (bytes): slot = l4 ^ ((l15>>1)&3)
    const int swzo = (l4 ^ ((l15 >> 1) & 3)) * 16;

#define STAGE(buf_, s_) do {                                                   \
        const int sp_ = (s_) >> 3;                                             \
        const int sc0_ = ((s_) & 7) * 32;                                      \
        const unsigned short* Ap_ = (sp_ == 2) ? z_lo : z_hi;                  \
        const unsigned short* Bp_ = (sp_ == 1) ? cb_lo : cb_hi;                \
        char* ab_ = (char*)(&As[buf_][0]) + wb;                                \
        char* bb_ = (char*)(&Bs[buf_][0]) + wb;                                \
        gl2lds16(Ap_ + (size_t)(nb + srow) * C_DIM + sc0_ + soct, ab_);        \
        gl2lds16(Bp_ + (size_t)(kb + srow) * C_DIM + sc0_ + soct, bb_);        \
        gl2lds16(Bp_ + (size_t)(kb + 128 + srow) * C_DIM + sc0_ + soct,        \
                 bb_ + 8192);                                                  \
    } while (0)

    f32x4 acc[4][4] = {};

    STAGE(0, 0);
    STAGE(1, 1);

#pragma unroll
    for (int s = 0; s < KSTEPS; ++s) {
        // counted wait: 2 tiles in flight (3 loads each); last iter drains.
        if (s < KSTEPS - 1) {
            asm volatile("s_waitcnt vmcnt(3)" ::: "memory");
        } else {
            asm volatile("s_waitcnt vmcnt(0)" ::: "memory");
        }
        __builtin_amdgcn_sched_barrier(0);
        __builtin_amdgcn_s_barrier();
        __builtin_amdgcn_sched_barrier(0);

        const int buf = s % 3;
        const char* Ab = (const char*)(&As[buf][0]);
        const char* Bb = (const char*)(&Bs[buf][0]);

        short8 av[4], bv[4];
#pragma unroll
        for (int mi = 0; mi < 4; ++mi)
            av[mi] = *reinterpret_cast<const short8*>(
                Ab + (wy * 64 + mi * 16 + l15) * 64 + swzo);
#pragma unroll
        for (int ci = 0; ci < 4; ++ci)
            bv[ci] = *reinterpret_cast<const short8*>(
                Bb + (wx * 64 + ci * 16 + l15) * 64 + swzo);

        if (s < KSTEPS - 2) STAGE((s + 2) % 3, s + 2);

#pragma unroll
        for (int mi = 0; mi < 4; ++mi)
#pragma unroll
            for (int ci = 0; ci < 4; ++ci)
                acc[mi][ci] = __builtin_amdgcn_mfma_f32_16x16x32_bf16(
                    av[mi], bv[ci], acc[mi][ci], 0, 0, 0);
    }
#undef STAGE

    // ---- epilogue: dist = zsq + esq - 2*dot; write + per-row partial argmin
    float zsv[4][4];
#pragma unroll
    for (int mi = 0; mi < 4; ++mi)
#pragma unroll
        for (int r = 0; r < 4; ++r)
            zsv[mi][r] = zsq[nb + wy * 64 + mi * 16 + l4 * 4 + r];
    float esv[4];
#pragma unroll
    for (int ci = 0; ci < 4; ++ci)
        esv[ci] = esq[kb + wx * 64 + ci * 16 + l15];

    float best[4][4];
    int bidx[4][4];
#pragma unroll
    for (int mi = 0; mi < 4; ++mi)
#pragma unroll
        for (int r = 0; r < 4; ++r) { best[mi][r] = 1e30f; bidx[mi][r] = K_CODES; }

#pragma unroll
    for (int mi = 0; mi < 4; ++mi) {
#pragma unroll
        for (int r = 0; r < 4; ++r) {
            int row = nb + wy * 64 + mi * 16 + l4 * 4 + r;
            float* drow = dist + (size_t)row * K_CODES;
#pragma unroll
            for (int ci = 0; ci < 4; ++ci) {     // ci ascending = k ascending
                int col = kb + wx * 64 + ci * 16 + l15;
                float d = zsv[mi][r] + esv[ci] - 2.f * acc[mi][ci][r];
                drow[col] = d;
                if (d < best[mi][r]) { best[mi][r] = d; bidx[mi][r] = col; }
            }
        }
    }

    // reduce across the 16-lane column group (xor masks 1,2,4,8 vary l15 only)
#pragma unroll
    for (int m = 1; m < 16; m <<= 1) {
#pragma unroll
        for (int mi = 0; mi < 4; ++mi)
#pragma unroll
            for (int r = 0; r < 4; ++r) {
                float ob = __shfl_xor(best[mi][r], m);
                int   oi = __shfl_xor(bidx[mi][r], m);
                if (ob < best[mi][r] || (ob == best[mi][r] && oi < bidx[mi][r])) {
                    best[mi][r] = ob; bidx[mi][r] = oi;
                }
            }
    }

    if (l15 == 0) {
#pragma unroll
        for (int mi = 0; mi < 4; ++mi)
#pragma unroll
            for (int r = 0; r < 4; ++r) {
                int rl = wy * 64 + mi * 16 + l4 * 4 + r;
                pb[rl][wx] = make_float2(best[mi][r], (float)bidx[mi][r]);
            }
    }
    __syncthreads();
    if (t < 128) {
        float2 bv2 = pb[t][0];
#pragma unroll
        for (int w = 1; w < 4; ++w) {
            float2 c = pb[t][w];              // ascending wx = ascending k
            if (c.x < bv2.x) bv2 = c;
        }
        partial[(size_t)kbi * N_ROWS + nb + t] = bv2;
    }
}

// -------- combine 4 kb-partials + one-hot encodings (fused) ------------------
__global__ __launch_bounds__(256) void combenc_kernel(
        const float2* __restrict__ partial, float* __restrict__ idx_out,
        int* __restrict__ idx_int, float* __restrict__ enc) {
    __shared__ int sidx[16];
    const int t = threadIdx.x;
    const int r0 = blockIdx.x * 16;
    if (t < 16) {
        int n = r0 + t;
        float2 bv = partial[n];
#pragma unroll
        for (int kb = 1; kb < 4; ++kb) {      // ascending kb = ascending k
            float2 c = partial[(size_t)kb * N_ROWS + n];
            if (c.x < bv.x) bv = c;
        }
        idx_out[n] = bv.y;
        idx_int[n] = (int)bv.y;
        sidx[t] = (int)bv.y;
    }
    __syncthreads();
    const int k0 = t * 4;
#pragma unroll 4
    for (int r = 0; r < 16; ++r) {
        int bi = sidx[r];
        float4 v;
        v.x = (k0 + 0 == bi) ? 1.0f : 0.0f;
        v.y = (k0 + 1 == bi) ? 1.0f : 0.0f;
        v.z = (k0 + 2 == bi) ? 1.0f : 0.0f;
        v.w = (k0 + 3 == bi) ? 1.0f : 0.0f;
        *reinterpret_cast<float4*>(enc + (size_t)(r0 + r) * K_CODES + k0) = v;
    }
}

// ---------------- perplexity: LDS histogram of idxi + reduce -----------------
__global__ __launch_bounds__(1024) void perp_kernel(const int* __restrict__ idxi,
                                                    float* __restrict__ out) {
    __shared__ int hist[K_CODES];
    __shared__ float wsum[16];
    const int t = threadIdx.x;
    hist[t] = 0;
    __syncthreads();
    for (int n = t; n < N_ROWS; n += 1024)
        atomicAdd(&hist[idxi[n]], 1);
    __syncthreads();
    float p = (float)hist[t] * (1.0f / (float)N_ROWS);
    float s = p * logf(p + 1e-10f);
#pragma unroll
    for (int off = 32; off > 0; off >>= 1) s += __shfl_down(s, off);
    if ((t & 63) == 0) wsum[t >> 6] = s;
    __syncthreads();
    if (t == 0) {
        float tot = 0.f;
#pragma unroll
        for (int w = 0; w < 16; ++w) tot += wsum[w];
        out[0] = expf(-tot);
    }
}

extern "C" void kernel_launch(void* const* d_in, const int* in_sizes, int n_in,
                              void* d_out, int out_size, void* d_ws, size_t ws_size,
                              hipStream_t stream) {
    const float* z  = (const float*)d_in[0];   // [32,256,32,32]
    const float* cb = (const float*)d_in[1];   // [1024,256]
    float* out  = (float*)d_out;
    float* dist = out + OFF_DIST;
    float* idxo = out + OFF_IDX;
    float* enc  = out + OFF_ENC;
    float* perp = out + OFF_PERP;

    // ws layout (bytes), ~1.3 MB
    char* wsb = (char*)d_ws;
    float*  zsq  = (float*)(wsb + 0);          // 131072 B
    float*  esq  = (float*)(wsb + 131072);     //   4096 B
    int*    idxi = (int*)(wsb + 135168);       // 131072 B
    float2* part = (float2*)(wsb + 266240);    // 4*32768*8 = 1048576 B

    // Big staging buffers live in the enc region of d_out (128 MB): written by
    // prep, read by dist, then overwritten by combenc (strict stream order).
    unsigned short* z_hi  = (unsigned short*)enc;
    unsigned short* z_lo  = z_hi + (size_t)N_ROWS * C_DIM;     // +16 MB
    unsigned short* cb_hi = z_lo + (size_t)N_ROWS * C_DIM;     // +32 MB
    unsigned short* cb_lo = cb_hi + (size_t)K_CODES * C_DIM;   // +32.5 MB

    prep_kernel<<<512, 256, 0, stream>>>(z, cb, z_hi, z_lo, cb_hi, cb_lo, zsq, esq);
    dist_mfma_kernel<<<1024, 512, 0, stream>>>(z_hi, z_lo, cb_hi, cb_lo,
                                               zsq, esq, dist, part);
    combenc_kernel<<<N_ROWS / 16, 256, 0, stream>>>(part, idxo, idxi, enc);
    perp_kernel<<<1, 1024, 0, stream>>>(idxi, perp);
}